// Round 1
// baseline (514.798 us; speedup 1.0000x reference)
//
#include <hip/hip_runtime.h>
#include <stdint.h>

// SNN: B=1024, D_IN=1024, D_H=2048, D_OUT=256, T=50, beta=0.9, thr=1.0
// Layer1 cur1 is time-invariant -> precompute spk1 for all t, layer2 is batched GEMM.
// Split-bf16 MFMA: spk in {0,1} exact in bf16; W = Whi + Wlo (2 RNE splits) -> fp32-accurate.

#define BATCH 1024
#define DIN   1024
#define DH    2048
#define DOUT  256
#define TSTEPS 50
#define TC     10      // time chunk
#define NCHUNK 5

typedef __bf16 bf16x8 __attribute__((ext_vector_type(8)));
typedef float  f32x4  __attribute__((ext_vector_type(4)));

__device__ __forceinline__ void gl2lds16(const void* g, void* l) {
  // width-16 async global->LDS; LDS dest is wave-uniform base + lane*16 (contiguous tid order)
  __builtin_amdgcn_global_load_lds(
      (const __attribute__((address_space(1))) uint32_t*)(uintptr_t)g,
      (__attribute__((address_space(3))) uint32_t*)(uint32_t)(uintptr_t)l,
      16, 0, 0);
}

__device__ __forceinline__ uint16_t f32_bf16_rne(float f) {
  uint32_t u = __float_as_uint(f);
  uint32_t r = u + 0x7FFFu + ((u >> 16) & 1u);
  return (uint16_t)(r >> 16);
}

// -------- split fp32 -> (hi, lo) bf16, lo = rne(v - hi) (v - hi is exact) --------
__global__ void split_kernel(const float* __restrict__ in, uint16_t* __restrict__ hi,
                             uint16_t* __restrict__ lo, int n) {
  int i = (blockIdx.x * 256 + threadIdx.x) * 4;
  if (i >= n) return;
  float4 v4 = *(const float4*)(in + i);
  float vv[4] = {v4.x, v4.y, v4.z, v4.w};
  uint32_t h[4], l[4];
#pragma unroll
  for (int k = 0; k < 4; ++k) {
    h[k] = f32_bf16_rne(vv[k]);
    float hf = __uint_as_float(h[k] << 16);
    l[k] = f32_bf16_rne(vv[k] - hf);
  }
  *(uint2*)(hi + i) = make_uint2(h[0] | (h[1] << 16), h[2] | (h[3] << 16));
  *(uint2*)(lo + i) = make_uint2(l[0] | (l[1] << 16), l[2] | (l[3] << 16));
}

// -------- GEMM1: cur1[1024,2048] = (xh+xl)[1024,1024] @ (w1h+w1l)[2048,1024]^T + b1 --------
// bf16x3: hi*hi + hi*lo + lo*hi. 128x128 tile, BK=32, 4 waves, 4x4 MFMA 16x16x32 per wave.
__global__ __launch_bounds__(256, 2) void gemm1_kernel(
    const uint16_t* __restrict__ Ah, const uint16_t* __restrict__ Al,
    const uint16_t* __restrict__ Bh, const uint16_t* __restrict__ Bl,
    const float* __restrict__ bias, float* __restrict__ C) {
  const int K = DIN, N = DH;
  __shared__ uint16_t sAh[128 * 32], sAl[128 * 32], sBh[128 * 32], sBl[128 * 32];
  int tid = threadIdx.x;
  int lane = tid & 63, wave = tid >> 6;
  int wm = (wave >> 1) * 64, wn = (wave & 1) * 64;
  int m0 = blockIdx.x * 128, n0 = blockIdx.y * 128;
  int rf = lane & 15;            // fragment row (m for A, n for B)
  int kq = (lane >> 4) * 8;      // fragment k offset

  f32x4 acc[4][4] = {};

  for (int k0 = 0; k0 < K; k0 += 32) {
#pragma unroll
    for (int ph = 0; ph < 2; ++ph) {
      int u = tid + ph * 256;          // 16B unit index; dest offset = u*16 B (contiguous)
      int r = u >> 2, c = (u & 3) * 8; // tile row / col (bf16 elems)
      const uint16_t* ga = Ah + (size_t)(m0 + r) * K + (k0 + c);
      const uint16_t* ga2 = Al + (size_t)(m0 + r) * K + (k0 + c);
      const uint16_t* gb = Bh + (size_t)(n0 + r) * K + (k0 + c);
      const uint16_t* gb2 = Bl + (size_t)(n0 + r) * K + (k0 + c);
      gl2lds16(ga,  &sAh[u * 8]);
      gl2lds16(ga2, &sAl[u * 8]);
      gl2lds16(gb,  &sBh[u * 8]);
      gl2lds16(gb2, &sBl[u * 8]);
    }
    __syncthreads();   // compiler drains vmcnt(0) before s_barrier

    bf16x8 ah[4], al[4], bh[4], bl[4];
#pragma unroll
    for (int i = 0; i < 4; ++i) {
      int ar = wm + i * 16 + rf;
      ah[i] = *(const bf16x8*)&sAh[ar * 32 + kq];
      al[i] = *(const bf16x8*)&sAl[ar * 32 + kq];
      int br = wn + i * 16 + rf;
      bh[i] = *(const bf16x8*)&sBh[br * 32 + kq];
      bl[i] = *(const bf16x8*)&sBl[br * 32 + kq];
    }
#pragma unroll
    for (int i = 0; i < 4; ++i)
#pragma unroll
      for (int j = 0; j < 4; ++j) {
        acc[i][j] = __builtin_amdgcn_mfma_f32_16x16x32_bf16(ah[i], bh[j], acc[i][j], 0, 0, 0);
        acc[i][j] = __builtin_amdgcn_mfma_f32_16x16x32_bf16(ah[i], bl[j], acc[i][j], 0, 0, 0);
        acc[i][j] = __builtin_amdgcn_mfma_f32_16x16x32_bf16(al[i], bh[j], acc[i][j], 0, 0, 0);
      }
    __syncthreads();
  }

  // C/D: col = lane&15, row = (lane>>4)*4 + reg
  int cq = (lane >> 4) * 4;
#pragma unroll
  for (int j = 0; j < 4; ++j) {
    int col = n0 + wn + j * 16 + rf;
    float bv = bias[col];
#pragma unroll
    for (int i = 0; i < 4; ++i) {
      size_t row = m0 + wm + i * 16 + cq;
      float* cp = C + row * N + col;
#pragma unroll
      for (int r = 0; r < 4; ++r) cp[(size_t)r * N] = acc[i][j][r] + bv;
    }
  }
}

// -------- GEMM2 (per chunk): cur2[TC*1024,256] = spk[TC*1024,2048] @ (w2h+w2l)[256,2048]^T + b2 --------
__global__ __launch_bounds__(256, 2) void gemm2_kernel(
    const uint16_t* __restrict__ A, const uint16_t* __restrict__ Bh,
    const uint16_t* __restrict__ Bl, const float* __restrict__ bias,
    float* __restrict__ C) {
  const int K = DH, N = DOUT;
  __shared__ uint16_t sA[128 * 32], sBh[128 * 32], sBl[128 * 32];
  int tid = threadIdx.x;
  int lane = tid & 63, wave = tid >> 6;
  int wm = (wave >> 1) * 64, wn = (wave & 1) * 64;
  int m0 = blockIdx.x * 128, n0 = blockIdx.y * 128;
  int rf = lane & 15;
  int kq = (lane >> 4) * 8;

  f32x4 acc[4][4] = {};

  for (int k0 = 0; k0 < K; k0 += 32) {
#pragma unroll
    for (int ph = 0; ph < 2; ++ph) {
      int u = tid + ph * 256;
      int r = u >> 2, c = (u & 3) * 8;
      gl2lds16(A  + (size_t)(m0 + r) * K + (k0 + c), &sA[u * 8]);
      gl2lds16(Bh + (size_t)(n0 + r) * K + (k0 + c), &sBh[u * 8]);
      gl2lds16(Bl + (size_t)(n0 + r) * K + (k0 + c), &sBl[u * 8]);
    }
    __syncthreads();

    bf16x8 a[4], bh[4], bl[4];
#pragma unroll
    for (int i = 0; i < 4; ++i) {
      int ar = wm + i * 16 + rf;
      a[i] = *(const bf16x8*)&sA[ar * 32 + kq];
      int br = wn + i * 16 + rf;
      bh[i] = *(const bf16x8*)&sBh[br * 32 + kq];
      bl[i] = *(const bf16x8*)&sBl[br * 32 + kq];
    }
#pragma unroll
    for (int i = 0; i < 4; ++i)
#pragma unroll
      for (int j = 0; j < 4; ++j) {
        acc[i][j] = __builtin_amdgcn_mfma_f32_16x16x32_bf16(a[i], bh[j], acc[i][j], 0, 0, 0);
        acc[i][j] = __builtin_amdgcn_mfma_f32_16x16x32_bf16(a[i], bl[j], acc[i][j], 0, 0, 0);
      }
    __syncthreads();
  }

  int cq = (lane >> 4) * 4;
#pragma unroll
  for (int j = 0; j < 4; ++j) {
    int col = n0 + wn + j * 16 + rf;
    float bv = bias[col];
#pragma unroll
    for (int i = 0; i < 4; ++i) {
      size_t row = m0 + wm + i * 16 + cq;
      float* cp = C + row * N + col;
#pragma unroll
      for (int r = 0; r < 4; ++r) cp[(size_t)r * N] = acc[i][j][r] + bv;
    }
  }
}

// -------- LIF layer 1 (one time-chunk): recurrence over TC steps, emit bf16 spikes + h_sum --------
__global__ void lif1_kernel(const float* __restrict__ cur1, float* __restrict__ mem1,
                            uint16_t* __restrict__ spk, float* __restrict__ hsum) {
#pragma clang fp contract(off)
  int idx = blockIdx.x * 256 + threadIdx.x;   // 262144 threads, 8 elems each
  int e0 = idx * 8;
  float4 c0 = *(const float4*)(cur1 + e0);
  float4 c1 = *(const float4*)(cur1 + e0 + 4);
  float4 ma = *(const float4*)(mem1 + e0);
  float4 mb = *(const float4*)(mem1 + e0 + 4);
  float m[8] = {ma.x, ma.y, ma.z, ma.w, mb.x, mb.y, mb.z, mb.w};
  float c[8] = {c0.x, c0.y, c0.z, c0.w, c1.x, c1.y, c1.z, c1.w};
  float hs[8] = {0, 0, 0, 0, 0, 0, 0, 0};
  for (int t = 0; t < TC; ++t) {
    uint32_t sb[8];
#pragma unroll
    for (int v = 0; v < 8; ++v) {
      float r = (m[v] > 1.0f) ? 1.0f : 0.0f;       // reset from PREVIOUS mem
      m[v] = 0.9f * m[v] + c[v] - r;               // contract(off): mul,add,sub like np
      bool s = (m[v] - 1.0f) > 0.0f;
      hs[v] += s ? 1.0f : 0.0f;
      sb[v] = s ? 0x3F80u : 0u;                    // bf16 1.0 / 0.0
    }
    uint4 pk = make_uint4(sb[0] | (sb[1] << 16), sb[2] | (sb[3] << 16),
                          sb[4] | (sb[5] << 16), sb[6] | (sb[7] << 16));
    *(uint4*)(spk + (size_t)t * (BATCH * DH) + e0) = pk;
  }
  *(float4*)(mem1 + e0)     = make_float4(m[0], m[1], m[2], m[3]);
  *(float4*)(mem1 + e0 + 4) = make_float4(m[4], m[5], m[6], m[7]);
  float4 h0 = *(float4*)(hsum + e0);
  float4 h1 = *(float4*)(hsum + e0 + 4);
  h0.x += hs[0]; h0.y += hs[1]; h0.z += hs[2]; h0.w += hs[3];
  h1.x += hs[4]; h1.y += hs[5]; h1.z += hs[6]; h1.w += hs[7];
  *(float4*)(hsum + e0)     = h0;
  *(float4*)(hsum + e0 + 4) = h1;
}

// -------- LIF layer 2 (one time-chunk) --------
__global__ void lif2_kernel(const float* __restrict__ cur2, float* __restrict__ mem2,
                            float* __restrict__ osum) {
#pragma clang fp contract(off)
  int idx = blockIdx.x * 256 + threadIdx.x;   // 262144 threads
  float m = mem2[idx];
  float os = 0.0f;
  for (int t = 0; t < TC; ++t) {
    float c = cur2[(size_t)t * (BATCH * DOUT) + idx];
    float r = (m > 1.0f) ? 1.0f : 0.0f;
    m = 0.9f * m + c - r;
    os += ((m - 1.0f) > 0.0f) ? 1.0f : 0.0f;
  }
  mem2[idx] = m;
  osum[idx] += os;
}

extern "C" void kernel_launch(void* const* d_in, const int* in_sizes, int n_in,
                              void* d_out, int out_size, void* d_ws, size_t ws_size,
                              hipStream_t stream) {
  const float* x  = (const float*)d_in[0];
  const float* W1 = (const float*)d_in[1];
  const float* b1 = (const float*)d_in[2];
  const float* W2 = (const float*)d_in[3];
  const float* b2 = (const float*)d_in[4];
  float* out = (float*)d_out;           // h_sum [1024*2048] then out_sum [1024*256]
  char* ws = (char*)d_ws;

  // ws layout (total 84,934,656 B)
  uint16_t* xh   = (uint16_t*)(ws + 0);
  uint16_t* xl   = (uint16_t*)(ws + 2097152);
  uint16_t* w1h  = (uint16_t*)(ws + 4194304);
  uint16_t* w1l  = (uint16_t*)(ws + 8388608);
  uint16_t* w2h  = (uint16_t*)(ws + 12582912);
  uint16_t* w2l  = (uint16_t*)(ws + 13631488);
  float*    cur1 = (float*)(ws + 14680064);
  float*    mem1 = (float*)(ws + 23068672);   // 8 MB
  float*    mem2 = (float*)(ws + 31457280);   // 1 MB (contiguous with mem1 for one memset)
  uint16_t* spkc = (uint16_t*)(ws + 32505856); // TC*1024*2048 bf16 = 41.9 MB
  float*    cur2c = (float*)(ws + 74448896);   // TC*1024*256 f32 = 10.5 MB

  hipMemsetAsync(d_out, 0, (size_t)out_size * sizeof(float), stream);
  hipMemsetAsync(ws + 23068672, 0, 8388608 + 1048576, stream);  // mem1 + mem2 = 0

  split_kernel<<<1024, 256, 0, stream>>>(x,  xh,  xl,  BATCH * DIN);
  split_kernel<<<2048, 256, 0, stream>>>(W1, w1h, w1l, DH * DIN);
  split_kernel<<<512,  256, 0, stream>>>(W2, w2h, w2l, DOUT * DH);

  gemm1_kernel<<<dim3(BATCH / 128, DH / 128), 256, 0, stream>>>(xh, xl, w1h, w1l, b1, cur1);

  for (int c = 0; c < NCHUNK; ++c) {
    lif1_kernel<<<(BATCH * DH) / (256 * 8), 256, 0, stream>>>(cur1, mem1, spkc, out);
    gemm2_kernel<<<dim3((TC * BATCH) / 128, DOUT / 128), 256, 0, stream>>>(spkc, w2h, w2l, b2, cur2c);
    lif2_kernel<<<(BATCH * DOUT) / 256, 256, 0, stream>>>(cur2c, mem2, out + BATCH * DH);
  }
}

// Round 2
// 263.017 us; speedup vs baseline: 1.9573x; 1.9573x over previous
//
#include <hip/hip_runtime.h>
#include <stdint.h>

// SNN: B=1024, D_IN=1024, D_H=2048, D_OUT=256, T=50, beta=0.9, thr=1.0
// cur1 time-invariant -> spk1 precomputable; layer2 = one big GEMM over M = T*B.
// gemm1: split-bf16 x3 (verified numerics). gemm2: i8 double-pass (spk exact in i8,
// W2 as 16-bit int pair hi*256+lo) -> exact i32 accumulation, 2x bf16 MFMA rate.

#define BATCH 1024
#define DIN   1024
#define DH    2048
#define DOUT  256
#define TSTEPS 50

typedef __bf16 bf16x8 __attribute__((ext_vector_type(8)));
typedef float  f32x4  __attribute__((ext_vector_type(4)));
typedef int    i32x4  __attribute__((ext_vector_type(4)));

__device__ __forceinline__ void gl2lds16(const void* g, void* l) {
  __builtin_amdgcn_global_load_lds(
      (const __attribute__((address_space(1))) uint32_t*)(uintptr_t)g,
      (__attribute__((address_space(3))) uint32_t*)(uint32_t)(uintptr_t)l,
      16, 0, 0);
}

__device__ __forceinline__ uint16_t f32_bf16_rne(float f) {
  uint32_t u = __float_as_uint(f);
  uint32_t r = u + 0x7FFFu + ((u >> 16) & 1u);
  return (uint16_t)(r >> 16);
}

// -------- split fp32 -> (hi, lo) bf16 --------
__global__ void split_kernel(const float* __restrict__ in, uint16_t* __restrict__ hi,
                             uint16_t* __restrict__ lo, int n) {
  int i = (blockIdx.x * 256 + threadIdx.x) * 4;
  if (i >= n) return;
  float4 v4 = *(const float4*)(in + i);
  float vv[4] = {v4.x, v4.y, v4.z, v4.w};
  uint32_t h[4], l[4];
#pragma unroll
  for (int k = 0; k < 4; ++k) {
    h[k] = f32_bf16_rne(vv[k]);
    float hf = __uint_as_float(h[k] << 16);
    l[k] = f32_bf16_rne(vv[k] - hf);
  }
  *(uint2*)(hi + i) = make_uint2(h[0] | (h[1] << 16), h[2] | (h[3] << 16));
  *(uint2*)(lo + i) = make_uint2(l[0] | (l[1] << 16), l[2] | (l[3] << 16));
}

// -------- W2 absmax (deterministic: order-independent max) --------
__global__ void maxabs_kernel(const float* __restrict__ in, unsigned* __restrict__ mx, int n) {
  int i = (blockIdx.x * 256 + threadIdx.x) * 4;
  float4 v = *(const float4*)(in + i);
  float m = fmaxf(fmaxf(fabsf(v.x), fabsf(v.y)), fmaxf(fabsf(v.z), fabsf(v.w)));
#pragma unroll
  for (int o = 32; o; o >>= 1) m = fmaxf(m, __shfl_down(m, o, 64));
  if ((threadIdx.x & 63) == 0) atomicMax(mx, __float_as_uint(m));  // all vals >= 0
}

// -------- W2 quantize: q = rint(w*S), S = 32512/max; q = hi*256 + lo, hi/lo in i8 --------
__global__ void quant_kernel(const float* __restrict__ in, const unsigned* __restrict__ mx,
                             int8_t* __restrict__ hi, int8_t* __restrict__ lo, int n) {
  int i = (blockIdx.x * 256 + threadIdx.x) * 4;
  if (i >= n) return;
  float S = 32512.0f / __uint_as_float(*mx);
  float4 v = *(const float4*)(in + i);
  float vv[4] = {v.x, v.y, v.z, v.w};
  int8_t h4[4], l4[4];
#pragma unroll
  for (int k = 0; k < 4; ++k) {
    int q = (int)rintf(vv[k] * S);
    int h = (q + 128) >> 8;            // floor((q+128)/256) in [-127,127]
    h4[k] = (int8_t)h;
    l4[k] = (int8_t)(q - (h << 8));    // in [-128,127]
  }
  *(uint32_t*)(hi + i) = (uint8_t)h4[0] | ((uint8_t)h4[1] << 8) | ((uint8_t)h4[2] << 16) | ((uint32_t)(uint8_t)h4[3] << 24);
  *(uint32_t*)(lo + i) = (uint8_t)l4[0] | ((uint8_t)l4[1] << 8) | ((uint8_t)l4[2] << 16) | ((uint32_t)(uint8_t)l4[3] << 24);
}

// -------- GEMM1: cur1[1024,2048] = x[1024,1024] @ W1[2048,1024]^T + b1, bf16x3 --------
// 64x128 tile (256 blocks), 4 waves in 2x2, each wave 2x4 MFMA 16x16x32.
__global__ __launch_bounds__(256, 2) void gemm1_kernel(
    const uint16_t* __restrict__ Ah, const uint16_t* __restrict__ Al,
    const uint16_t* __restrict__ Bh, const uint16_t* __restrict__ Bl,
    const float* __restrict__ bias, float* __restrict__ C) {
  const int K = DIN, N = DH;
  __shared__ uint16_t sAh[64 * 32], sAl[64 * 32], sBh[128 * 32], sBl[128 * 32];
  int tid = threadIdx.x;
  int lane = tid & 63, wave = tid >> 6;
  int wm = (wave >> 1) * 32, wn = (wave & 1) * 64;
  int m0 = blockIdx.x * 64, n0 = blockIdx.y * 128;
  int rf = lane & 15;
  int kq = (lane >> 4) * 8;

  f32x4 acc[2][4] = {};

  for (int k0 = 0; k0 < K; k0 += 32) {
    {
      int u = tid;                       // A: 64x32 = 256 16B-units
      int r = u >> 2, c = (u & 3) * 8;
      gl2lds16(Ah + (size_t)(m0 + r) * K + (k0 + c), &sAh[u * 8]);
      gl2lds16(Al + (size_t)(m0 + r) * K + (k0 + c), &sAl[u * 8]);
    }
#pragma unroll
    for (int ph = 0; ph < 2; ++ph) {     // B: 128x32 = 512 units
      int u = tid + ph * 256;
      int r = u >> 2, c = (u & 3) * 8;
      gl2lds16(Bh + (size_t)(n0 + r) * K + (k0 + c), &sBh[u * 8]);
      gl2lds16(Bl + (size_t)(n0 + r) * K + (k0 + c), &sBl[u * 8]);
    }
    __syncthreads();

    bf16x8 ah[2], al[2], bh[4], bl[4];
#pragma unroll
    for (int i = 0; i < 2; ++i) {
      int ar = wm + i * 16 + rf;
      ah[i] = *(const bf16x8*)&sAh[ar * 32 + kq];
      al[i] = *(const bf16x8*)&sAl[ar * 32 + kq];
    }
#pragma unroll
    for (int j = 0; j < 4; ++j) {
      int br = wn + j * 16 + rf;
      bh[j] = *(const bf16x8*)&sBh[br * 32 + kq];
      bl[j] = *(const bf16x8*)&sBl[br * 32 + kq];
    }
#pragma unroll
    for (int i = 0; i < 2; ++i)
#pragma unroll
      for (int j = 0; j < 4; ++j) {
        acc[i][j] = __builtin_amdgcn_mfma_f32_16x16x32_bf16(ah[i], bh[j], acc[i][j], 0, 0, 0);
        acc[i][j] = __builtin_amdgcn_mfma_f32_16x16x32_bf16(ah[i], bl[j], acc[i][j], 0, 0, 0);
        acc[i][j] = __builtin_amdgcn_mfma_f32_16x16x32_bf16(al[i], bh[j], acc[i][j], 0, 0, 0);
      }
    __syncthreads();
  }

  int cq = (lane >> 4) * 4;              // C/D: col=lane&15, row=(lane>>4)*4+reg
#pragma unroll
  for (int j = 0; j < 4; ++j) {
    int col = n0 + wn + j * 16 + rf;
    float bv = bias[col];
#pragma unroll
    for (int i = 0; i < 2; ++i) {
      size_t row = m0 + wm + i * 16 + cq;
      float* cp = C + row * N + col;
#pragma unroll
      for (int r = 0; r < 4; ++r) cp[(size_t)r * N] = acc[i][j][r] + bv;
    }
  }
}

// -------- GEMM2: cur2[M,256] = spk_i8[M,2048] @ W2q[256,2048]^T, i8 double pass --------
// 128x128 tile, BK=64, 4 waves 2x2, each wave 4x4 MFMA 16x16x64 x2 passes.
__global__ __launch_bounds__(256, 2) void gemm2_kernel(
    const int8_t* __restrict__ A, const int8_t* __restrict__ Bh,
    const int8_t* __restrict__ Bl, const float* __restrict__ bias,
    const unsigned* __restrict__ mx, float* __restrict__ C) {
  const int K = DH, N = DOUT;
  __shared__ int8_t sA[128 * 64], sBh[128 * 64], sBl[128 * 64];
  int tid = threadIdx.x;
  int lane = tid & 63, wave = tid >> 6;
  int wm = (wave >> 1) * 64, wn = (wave & 1) * 64;
  int m0 = blockIdx.x * 128, n0 = blockIdx.y * 128;
  int rf = lane & 15;
  int kb = (lane >> 4) * 16;             // byte (=elem) offset in 64-byte K row

  i32x4 acch[4][4] = {};
  i32x4 accl[4][4] = {};

  for (int k0 = 0; k0 < K; k0 += 64) {
#pragma unroll
    for (int ph = 0; ph < 2; ++ph) {     // 128x64 B = 512 16B-units per array
      int u = tid + ph * 256;
      int r = u >> 2, c = (u & 3) * 16;
      gl2lds16(A  + (size_t)(m0 + r) * K + (k0 + c), &sA[u * 16]);
      gl2lds16(Bh + (size_t)(n0 + r) * K + (k0 + c), &sBh[u * 16]);
      gl2lds16(Bl + (size_t)(n0 + r) * K + (k0 + c), &sBl[u * 16]);
    }
    __syncthreads();

    i32x4 a[4], bh[4], bl[4];
#pragma unroll
    for (int i = 0; i < 4; ++i) {
      a[i]  = *(const i32x4*)&sA[(wm + i * 16 + rf) * 64 + kb];
      bh[i] = *(const i32x4*)&sBh[(wn + i * 16 + rf) * 64 + kb];
      bl[i] = *(const i32x4*)&sBl[(wn + i * 16 + rf) * 64 + kb];
    }
#pragma unroll
    for (int i = 0; i < 4; ++i)
#pragma unroll
      for (int j = 0; j < 4; ++j) {
        acch[i][j] = __builtin_amdgcn_mfma_i32_16x16x64_i8(a[i], bh[j], acch[i][j], 0, 0, 0);
        accl[i][j] = __builtin_amdgcn_mfma_i32_16x16x64_i8(a[i], bl[j], accl[i][j], 0, 0, 0);
      }
    __syncthreads();
  }

  float invS = __uint_as_float(*mx) * (1.0f / 32512.0f);
  int cq = (lane >> 4) * 4;
#pragma unroll
  for (int j = 0; j < 4; ++j) {
    int col = n0 + wn + j * 16 + rf;
    float bv = bias[col];
#pragma unroll
    for (int i = 0; i < 4; ++i) {
      size_t row = m0 + wm + i * 16 + cq;
      float* cp = C + row * N + col;
#pragma unroll
      for (int r = 0; r < 4; ++r) {
        int q = acch[i][j][r] * 256 + accl[i][j][r];   // exact i32
        cp[(size_t)r * N] = (float)q * invS + bv;
      }
    }
  }
}

// -------- LIF layer 1 (tc steps): emit i8 spikes + accumulate h_sum --------
__global__ void lif1_kernel(const float* __restrict__ cur1, float* __restrict__ mem1,
                            int8_t* __restrict__ spk, float* __restrict__ hsum, int tc) {
#pragma clang fp contract(off)
  int idx = blockIdx.x * 256 + threadIdx.x;   // 262144 threads, 8 elems each
  int e0 = idx * 8;
  float4 c0 = *(const float4*)(cur1 + e0);
  float4 c1 = *(const float4*)(cur1 + e0 + 4);
  float4 ma = *(const float4*)(mem1 + e0);
  float4 mb = *(const float4*)(mem1 + e0 + 4);
  float m[8] = {ma.x, ma.y, ma.z, ma.w, mb.x, mb.y, mb.z, mb.w};
  float c[8] = {c0.x, c0.y, c0.z, c0.w, c1.x, c1.y, c1.z, c1.w};
  float hs[8] = {0, 0, 0, 0, 0, 0, 0, 0};
  for (int t = 0; t < tc; ++t) {
    uint32_t b0 = 0, b1 = 0;
#pragma unroll
    for (int v = 0; v < 8; ++v) {
      float r = (m[v] > 1.0f) ? 1.0f : 0.0f;   // reset from PREVIOUS mem
      m[v] = 0.9f * m[v] + c[v] - r;           // contract(off): mul,add,sub like np
      bool s = (m[v] - 1.0f) > 0.0f;
      hs[v] += s ? 1.0f : 0.0f;
      uint32_t bit = s ? 1u : 0u;
      if (v < 4) b0 |= bit << (8 * v); else b1 |= bit << (8 * (v - 4));
    }
    *(uint2*)(spk + (size_t)t * (BATCH * DH) + e0) = make_uint2(b0, b1);
  }
  *(float4*)(mem1 + e0)     = make_float4(m[0], m[1], m[2], m[3]);
  *(float4*)(mem1 + e0 + 4) = make_float4(m[4], m[5], m[6], m[7]);
  float4 h0 = *(float4*)(hsum + e0);
  float4 h1 = *(float4*)(hsum + e0 + 4);
  h0.x += hs[0]; h0.y += hs[1]; h0.z += hs[2]; h0.w += hs[3];
  h1.x += hs[4]; h1.y += hs[5]; h1.z += hs[6]; h1.w += hs[7];
  *(float4*)(hsum + e0)     = h0;
  *(float4*)(hsum + e0 + 4) = h1;
}

// -------- LIF layer 2 (tc steps) --------
__global__ void lif2_kernel(const float* __restrict__ cur2, float* __restrict__ mem2,
                            float* __restrict__ osum, int tc) {
#pragma clang fp contract(off)
  int idx = blockIdx.x * 256 + threadIdx.x;   // 262144 threads
  float m = mem2[idx];
  float os = 0.0f;
  for (int t = 0; t < tc; ++t) {
    float c = cur2[(size_t)t * (BATCH * DOUT) + idx];
    float r = (m > 1.0f) ? 1.0f : 0.0f;
    m = 0.9f * m + c - r;
    os += ((m - 1.0f) > 0.0f) ? 1.0f : 0.0f;
  }
  mem2[idx] = m;
  osum[idx] += os;
}

extern "C" void kernel_launch(void* const* d_in, const int* in_sizes, int n_in,
                              void* d_out, int out_size, void* d_ws, size_t ws_size,
                              hipStream_t stream) {
  const float* x  = (const float*)d_in[0];
  const float* W1 = (const float*)d_in[1];
  const float* b1 = (const float*)d_in[2];
  const float* W2 = (const float*)d_in[3];
  const float* b2 = (const float*)d_in[4];
  float* out = (float*)d_out;           // h_sum [1024*2048] then out_sum [1024*256]
  char* ws = (char*)d_ws;

  // pick largest time-chunk that fits ws (constant across calls -> graph-safe)
  const size_t fixed = 32 * 1024 * 1024;  // splits+scale+cur1+mem1+mem2 (~30.4 MB) + slack
  int tc = 10;
  if (ws_size >= fixed + 50ull * (2097152 + 1048576)) tc = 50;
  else if (ws_size >= fixed + 25ull * (2097152 + 1048576)) tc = 25;
  int nchunk = TSTEPS / tc;

  size_t off = 0;
  auto alloc = [&](size_t b) { size_t p = off; off = (off + b + 255) & ~(size_t)255; return p; };
  uint16_t* xh   = (uint16_t*)(ws + alloc(2097152));
  uint16_t* xl   = (uint16_t*)(ws + alloc(2097152));
  uint16_t* w1h  = (uint16_t*)(ws + alloc(4194304));
  uint16_t* w1l  = (uint16_t*)(ws + alloc(4194304));
  int8_t*   w2h  = (int8_t*)(ws + alloc(524288));
  int8_t*   w2l  = (int8_t*)(ws + alloc(524288));
  unsigned* w2mx = (unsigned*)(ws + alloc(256));
  float*    cur1 = (float*)(ws + alloc(8388608));
  char*     memz = ws + off;                         // mem1+mem2 contiguous: one memset
  float*    mem1 = (float*)(ws + alloc(8388608));
  float*    mem2 = (float*)(ws + alloc(1048576));
  int8_t*   spkc = (int8_t*)(ws + alloc((size_t)tc * BATCH * DH));
  float*    cur2c = (float*)(ws + alloc((size_t)tc * BATCH * DOUT * 4));

  hipMemsetAsync(d_out, 0, (size_t)out_size * sizeof(float), stream);
  hipMemsetAsync(memz, 0, 8388608 + 1048576 + 512, stream);
  hipMemsetAsync(w2mx, 0, 4, stream);

  split_kernel<<<1024, 256, 0, stream>>>(x,  xh,  xl,  BATCH * DIN);
  split_kernel<<<2048, 256, 0, stream>>>(W1, w1h, w1l, DH * DIN);
  maxabs_kernel<<<512, 256, 0, stream>>>(W2, w2mx, DOUT * DH);
  quant_kernel<<<512, 256, 0, stream>>>(W2, w2mx, w2h, w2l, DOUT * DH);

  gemm1_kernel<<<dim3(BATCH / 64, DH / 128), 256, 0, stream>>>(xh, xl, w1h, w1l, b1, cur1);

  for (int c = 0; c < nchunk; ++c) {
    lif1_kernel<<<(BATCH * DH) / (256 * 8), 256, 0, stream>>>(cur1, mem1, spkc, out, tc);
    gemm2_kernel<<<dim3((tc * BATCH) / 128, DOUT / 128), 256, 0, stream>>>(
        spkc, w2h, w2l, b2, w2mx, cur2c);
    lif2_kernel<<<(BATCH * DOUT) / 256, 256, 0, stream>>>(cur2c, mem2, out + BATCH * DH, tc);
  }
}

// Round 3
// 243.224 us; speedup vs baseline: 2.1166x; 1.0814x over previous
//
#include <hip/hip_runtime.h>
#include <stdint.h>

// SNN: B=1024, D_IN=1024, D_H=2048, D_OUT=256, T=50, beta=0.9, thr=1.0
// cur1 time-invariant -> spk1 precomputable; layer2 = one GEMM over M = T*B = 51200.
// gemm1: split-bf16 x3. gemm2: i8 double-pass (W2 = hi*256+lo, spk exact in i8),
// 32x32x32 i8 MFMA, 128x64 tiles, LDS rotate-swizzle to break 64B-stride bank aliasing.

#define BATCH 1024
#define DIN   1024
#define DH    2048
#define DOUT  256
#define TSTEPS 50

typedef __bf16 bf16x8 __attribute__((ext_vector_type(8)));
typedef float  f32x4  __attribute__((ext_vector_type(4)));
typedef int    i32x4  __attribute__((ext_vector_type(4)));
typedef int    i32x16 __attribute__((ext_vector_type(16)));

__device__ __forceinline__ void gl2lds16(const void* g, void* l) {
  __builtin_amdgcn_global_load_lds(
      (const __attribute__((address_space(1))) uint32_t*)(uintptr_t)g,
      (__attribute__((address_space(3))) uint32_t*)(uint32_t)(uintptr_t)l,
      16, 0, 0);
}

__device__ __forceinline__ uint16_t f32_bf16_rne(float f) {
  uint32_t u = __float_as_uint(f);
  uint32_t r = u + 0x7FFFu + ((u >> 16) & 1u);
  return (uint16_t)(r >> 16);
}

// -------- split fp32 -> (hi, lo) bf16 --------
__global__ void split_kernel(const float* __restrict__ in, uint16_t* __restrict__ hi,
                             uint16_t* __restrict__ lo, int n) {
  int i = (blockIdx.x * 256 + threadIdx.x) * 4;
  if (i >= n) return;
  float4 v4 = *(const float4*)(in + i);
  float vv[4] = {v4.x, v4.y, v4.z, v4.w};
  uint32_t h[4], l[4];
#pragma unroll
  for (int k = 0; k < 4; ++k) {
    h[k] = f32_bf16_rne(vv[k]);
    float hf = __uint_as_float(h[k] << 16);
    l[k] = f32_bf16_rne(vv[k] - hf);
  }
  *(uint2*)(hi + i) = make_uint2(h[0] | (h[1] << 16), h[2] | (h[3] << 16));
  *(uint2*)(lo + i) = make_uint2(l[0] | (l[1] << 16), l[2] | (l[3] << 16));
}

// -------- W2 absmax (order-independent max -> deterministic) --------
__global__ void maxabs_kernel(const float* __restrict__ in, unsigned* __restrict__ mx, int n) {
  int i = (blockIdx.x * 256 + threadIdx.x) * 4;
  float4 v = *(const float4*)(in + i);
  float m = fmaxf(fmaxf(fabsf(v.x), fabsf(v.y)), fmaxf(fabsf(v.z), fabsf(v.w)));
#pragma unroll
  for (int o = 32; o; o >>= 1) m = fmaxf(m, __shfl_down(m, o, 64));
  if ((threadIdx.x & 63) == 0) atomicMax(mx, __float_as_uint(m));
}

// -------- W2 quantize: q = rint(w*S), S = 32512/max; q = hi*256 + lo --------
__global__ void quant_kernel(const float* __restrict__ in, const unsigned* __restrict__ mx,
                             int8_t* __restrict__ hi, int8_t* __restrict__ lo, int n) {
  int i = (blockIdx.x * 256 + threadIdx.x) * 4;
  if (i >= n) return;
  float S = 32512.0f / __uint_as_float(*mx);
  float4 v = *(const float4*)(in + i);
  float vv[4] = {v.x, v.y, v.z, v.w};
  int8_t h4[4], l4[4];
#pragma unroll
  for (int k = 0; k < 4; ++k) {
    int q = (int)rintf(vv[k] * S);
    int h = (q + 128) >> 8;
    h4[k] = (int8_t)h;
    l4[k] = (int8_t)(q - (h << 8));
  }
  *(uint32_t*)(hi + i) = (uint8_t)h4[0] | ((uint8_t)h4[1] << 8) | ((uint8_t)h4[2] << 16) | ((uint32_t)(uint8_t)h4[3] << 24);
  *(uint32_t*)(lo + i) = (uint8_t)l4[0] | ((uint8_t)l4[1] << 8) | ((uint8_t)l4[2] << 16) | ((uint32_t)(uint8_t)l4[3] << 24);
}

// -------- GEMM1: cur1[1024,2048] = x @ W1^T + b1, bf16x3, 64x64 tile --------
// LDS rows are 64 B; chunk c of row r staged at sub-slot (c+(r>>1))&3 (bank swizzle).
__global__ __launch_bounds__(256, 4) void gemm1_kernel(
    const uint16_t* __restrict__ Ah, const uint16_t* __restrict__ Al,
    const uint16_t* __restrict__ Bh, const uint16_t* __restrict__ Bl,
    const float* __restrict__ bias, float* __restrict__ C) {
  const int K = DIN, N = DH;
  __shared__ uint16_t sAh[64 * 32], sAl[64 * 32], sBh[64 * 32], sBl[64 * 32];
  int tid = threadIdx.x;
  int lane = tid & 63, wave = tid >> 6;
  int wm = (wave >> 1) * 32, wn = (wave & 1) * 32;
  int m0 = blockIdx.x * 64, n0 = blockIdx.y * 64;
  int rf = lane & 15;
  int cc = lane >> 4;                    // k-chunk index (16B units)

  f32x4 acc[2][2] = {};

  // staging unit: r = tid>>2, LDS slot tid&3, global chunk ((tid&3)-(r>>1))&3
  int sr = tid >> 2;
  int sc = (((tid & 3) - (sr >> 1)) & 3) * 8;   // global col in bf16 elems

  for (int k0 = 0; k0 < K; k0 += 32) {
    gl2lds16(Ah + (size_t)(m0 + sr) * K + (k0 + sc), &sAh[tid * 8]);
    gl2lds16(Al + (size_t)(m0 + sr) * K + (k0 + sc), &sAl[tid * 8]);
    gl2lds16(Bh + (size_t)(n0 + sr) * K + (k0 + sc), &sBh[tid * 8]);
    gl2lds16(Bl + (size_t)(n0 + sr) * K + (k0 + sc), &sBl[tid * 8]);
    __syncthreads();

    bf16x8 ah[2], al[2], bh[2], bl[2];
#pragma unroll
    for (int i = 0; i < 2; ++i) {
      int R = wm + i * 16 + rf;
      int sl = ((cc + (R >> 1)) & 3) * 8;
      ah[i] = *(const bf16x8*)&sAh[R * 32 + sl];
      al[i] = *(const bf16x8*)&sAl[R * 32 + sl];
      int Rb = wn + i * 16 + rf;
      int slb = ((cc + (Rb >> 1)) & 3) * 8;
      bh[i] = *(const bf16x8*)&sBh[Rb * 32 + slb];
      bl[i] = *(const bf16x8*)&sBl[Rb * 32 + slb];
    }
#pragma unroll
    for (int i = 0; i < 2; ++i)
#pragma unroll
      for (int j = 0; j < 2; ++j) {
        acc[i][j] = __builtin_amdgcn_mfma_f32_16x16x32_bf16(ah[i], bh[j], acc[i][j], 0, 0, 0);
        acc[i][j] = __builtin_amdgcn_mfma_f32_16x16x32_bf16(ah[i], bl[j], acc[i][j], 0, 0, 0);
        acc[i][j] = __builtin_amdgcn_mfma_f32_16x16x32_bf16(al[i], bh[j], acc[i][j], 0, 0, 0);
      }
    __syncthreads();
  }

  int cq = (lane >> 4) * 4;              // C/D 16x16: col=lane&15, row=(lane>>4)*4+reg
#pragma unroll
  for (int j = 0; j < 2; ++j) {
    int col = n0 + wn + j * 16 + rf;
    float bv = bias[col];
#pragma unroll
    for (int i = 0; i < 2; ++i) {
      size_t row = m0 + wm + i * 16 + cq;
      float* cp = C + row * N + col;
#pragma unroll
      for (int r = 0; r < 4; ++r) cp[(size_t)r * N] = acc[i][j][r] + bv;
    }
  }
}

// -------- GEMM2: cur2[M,256] = spk_i8[M,2048] @ W2q^T, 32x32x32 i8, 128x64 tile --------
__global__ __launch_bounds__(256, 3) void gemm2_kernel(
    const int8_t* __restrict__ A, const int8_t* __restrict__ Bh,
    const int8_t* __restrict__ Bl, const float* __restrict__ bias,
    const unsigned* __restrict__ mx, float* __restrict__ C) {
  const int K = DH, N = DOUT;
  __shared__ int8_t sA[128 * 64], sBh[64 * 64], sBl[64 * 64];
  int tid = threadIdx.x;
  int lane = tid & 63, wave = tid >> 6;
  int m0 = blockIdx.x * 128, n0 = blockIdx.y * 64;
  int rm = lane & 31;
  int half = lane >> 5;

  i32x16 acch[2] = {};
  i32x16 accl[2] = {};

  for (int k0 = 0; k0 < K; k0 += 64) {
#pragma unroll
    for (int ph = 0; ph < 2; ++ph) {     // A: 128 rows x 64 B = 512 units
      int u = tid + ph * 256;
      int r = u >> 2;
      int c = (((u & 3) - (r >> 1)) & 3) * 16;   // swizzled global chunk
      gl2lds16(A + (size_t)(m0 + r) * K + (k0 + c), &sA[u * 16]);
    }
    {                                    // B: 64 rows x 64 B = 256 units each
      int r = tid >> 2;
      int c = (((tid & 3) - (r >> 1)) & 3) * 16;
      gl2lds16(Bh + (size_t)(n0 + r) * K + (k0 + c), &sBh[tid * 16]);
      gl2lds16(Bl + (size_t)(n0 + r) * K + (k0 + c), &sBl[tid * 16]);
    }
    __syncthreads();

    // frag: A[m=rm][k = ks*32 + half*16 + j]; chunk idx = ks*2+half, swizzled by row
    i32x4 a[2], bhf[2][2], blf[2][2];
#pragma unroll
    for (int ks = 0; ks < 2; ++ks) {
      int Ra = wave * 32 + rm;
      int sla = ((ks * 2 + half + (Ra >> 1)) & 3) * 16;
      a[ks] = *(const i32x4*)&sA[Ra * 64 + sla];
#pragma unroll
      for (int n = 0; n < 2; ++n) {
        int Rb = n * 32 + rm;
        int slb = ((ks * 2 + half + (Rb >> 1)) & 3) * 16;
        bhf[n][ks] = *(const i32x4*)&sBh[Rb * 64 + slb];
        blf[n][ks] = *(const i32x4*)&sBl[Rb * 64 + slb];
      }
    }
#pragma unroll
    for (int ks = 0; ks < 2; ++ks)
#pragma unroll
      for (int n = 0; n < 2; ++n) {
        acch[n] = __builtin_amdgcn_mfma_i32_32x32x32_i8(a[ks], bhf[n][ks], acch[n], 0, 0, 0);
        accl[n] = __builtin_amdgcn_mfma_i32_32x32x32_i8(a[ks], blf[n][ks], accl[n], 0, 0, 0);
      }
    __syncthreads();
  }

  // C/D 32x32: col = lane&31, row = (r&3) + 8*(r>>2) + 4*(lane>>5)
  float invS = __uint_as_float(*mx) * (1.0f / 32512.0f);
#pragma unroll
  for (int n = 0; n < 2; ++n) {
    int col = n0 + n * 32 + rm;
    float bv = bias[col];
#pragma unroll
    for (int r = 0; r < 16; ++r) {
      int row = m0 + wave * 32 + (r & 3) + 8 * (r >> 2) + 4 * half;
      int q = acch[n][r] * 256 + accl[n][r];     // exact i32
      C[(size_t)row * N + col] = (float)q * invS + bv;
    }
  }
}

// -------- LIF layer 1: recurrence, emit i8 spikes + h_sum --------
__global__ void lif1_kernel(const float* __restrict__ cur1, float* __restrict__ mem1,
                            int8_t* __restrict__ spk, float* __restrict__ hsum,
                            int tc, int init, int save_mem) {
#pragma clang fp contract(off)
  int idx = blockIdx.x * 256 + threadIdx.x;
  int e0 = idx * 8;
  float4 c0 = *(const float4*)(cur1 + e0);
  float4 c1 = *(const float4*)(cur1 + e0 + 4);
  float m[8] = {0, 0, 0, 0, 0, 0, 0, 0};
  if (!init) {
    float4 ma = *(const float4*)(mem1 + e0);
    float4 mb = *(const float4*)(mem1 + e0 + 4);
    m[0] = ma.x; m[1] = ma.y; m[2] = ma.z; m[3] = ma.w;
    m[4] = mb.x; m[5] = mb.y; m[6] = mb.z; m[7] = mb.w;
  }
  float c[8] = {c0.x, c0.y, c0.z, c0.w, c1.x, c1.y, c1.z, c1.w};
  float hs[8] = {0, 0, 0, 0, 0, 0, 0, 0};
  for (int t = 0; t < tc; ++t) {
    uint32_t b0 = 0, b1 = 0;
#pragma unroll
    for (int v = 0; v < 8; ++v) {
      float r = (m[v] > 1.0f) ? 1.0f : 0.0f;   // reset from PREVIOUS mem
      m[v] = 0.9f * m[v] + c[v] - r;           // contract(off): mul,add,sub like np
      bool s = (m[v] - 1.0f) > 0.0f;
      hs[v] += s ? 1.0f : 0.0f;
      uint32_t bit = s ? 1u : 0u;
      if (v < 4) b0 |= bit << (8 * v); else b1 |= bit << (8 * (v - 4));
    }
    *(uint2*)(spk + (size_t)t * (BATCH * DH) + e0) = make_uint2(b0, b1);
  }
  if (save_mem) {
    *(float4*)(mem1 + e0)     = make_float4(m[0], m[1], m[2], m[3]);
    *(float4*)(mem1 + e0 + 4) = make_float4(m[4], m[5], m[6], m[7]);
  }
  float4 h0, h1;
  if (init) {
    h0 = make_float4(hs[0], hs[1], hs[2], hs[3]);
    h1 = make_float4(hs[4], hs[5], hs[6], hs[7]);
  } else {
    h0 = *(float4*)(hsum + e0);
    h1 = *(float4*)(hsum + e0 + 4);
    h0.x += hs[0]; h0.y += hs[1]; h0.z += hs[2]; h0.w += hs[3];
    h1.x += hs[4]; h1.y += hs[5]; h1.z += hs[6]; h1.w += hs[7];
  }
  *(float4*)(hsum + e0)     = h0;
  *(float4*)(hsum + e0 + 4) = h1;
}

// -------- LIF layer 2 --------
__global__ void lif2_kernel(const float* __restrict__ cur2, float* __restrict__ mem2,
                            float* __restrict__ osum, int tc, int init, int save_mem) {
#pragma clang fp contract(off)
  int idx = blockIdx.x * 256 + threadIdx.x;
  float m = init ? 0.0f : mem2[idx];
  float os = 0.0f;
  for (int t = 0; t < tc; ++t) {
    float c = cur2[(size_t)t * (BATCH * DOUT) + idx];
    float r = (m > 1.0f) ? 1.0f : 0.0f;
    m = 0.9f * m + c - r;
    os += ((m - 1.0f) > 0.0f) ? 1.0f : 0.0f;
  }
  if (save_mem) mem2[idx] = m;
  osum[idx] = init ? os : (osum[idx] + os);
}

extern "C" void kernel_launch(void* const* d_in, const int* in_sizes, int n_in,
                              void* d_out, int out_size, void* d_ws, size_t ws_size,
                              hipStream_t stream) {
  const float* x  = (const float*)d_in[0];
  const float* W1 = (const float*)d_in[1];
  const float* b1 = (const float*)d_in[2];
  const float* W2 = (const float*)d_in[3];
  const float* b2 = (const float*)d_in[4];
  float* out = (float*)d_out;           // h_sum [1024*2048] then out_sum [1024*256]
  char* ws = (char*)d_ws;

  const size_t fixed = 32 * 1024 * 1024;
  int tc = 10;
  if (ws_size >= fixed + 50ull * (2097152 + 1048576)) tc = 50;
  else if (ws_size >= fixed + 25ull * (2097152 + 1048576)) tc = 25;
  int nchunk = TSTEPS / tc;

  size_t off = 0;
  auto alloc = [&](size_t b) { size_t p = off; off = (off + b + 255) & ~(size_t)255; return p; };
  uint16_t* xh   = (uint16_t*)(ws + alloc(2097152));
  uint16_t* xl   = (uint16_t*)(ws + alloc(2097152));
  uint16_t* w1h  = (uint16_t*)(ws + alloc(4194304));
  uint16_t* w1l  = (uint16_t*)(ws + alloc(4194304));
  int8_t*   w2h  = (int8_t*)(ws + alloc(524288));
  int8_t*   w2l  = (int8_t*)(ws + alloc(524288));
  unsigned* w2mx = (unsigned*)(ws + alloc(256));
  float*    cur1 = (float*)(ws + alloc(8388608));
  float*    mem1 = (float*)(ws + alloc(8388608));
  float*    mem2 = (float*)(ws + alloc(1048576));
  int8_t*   spkc = (int8_t*)(ws + alloc((size_t)tc * BATCH * DH));
  float*    cur2c = (float*)(ws + alloc((size_t)tc * BATCH * DOUT * 4));

  hipMemsetAsync(w2mx, 0, 4, stream);
  if (nchunk > 1) {
    // multi-chunk fallback needs zeroed mem state (init flag only covers chunk 0's read)
    hipMemsetAsync(mem1, 0, 8388608, stream);
    hipMemsetAsync(mem2, 0, 1048576, stream);
  }

  split_kernel<<<1024, 256, 0, stream>>>(x,  xh,  xl,  BATCH * DIN);
  split_kernel<<<2048, 256, 0, stream>>>(W1, w1h, w1l, DH * DIN);
  maxabs_kernel<<<512, 256, 0, stream>>>(W2, w2mx, DOUT * DH);
  quant_kernel<<<512, 256, 0, stream>>>(W2, w2mx, w2h, w2l, DOUT * DH);

  gemm1_kernel<<<dim3(BATCH / 64, DH / 64), 256, 0, stream>>>(xh, xl, w1h, w1l, b1, cur1);

  int save = (nchunk > 1) ? 1 : 0;
  for (int c = 0; c < nchunk; ++c) {
    int init = (c == 0) ? 1 : 0;
    lif1_kernel<<<(BATCH * DH) / (256 * 8), 256, 0, stream>>>(cur1, mem1, spkc, out, tc, init, save);
    gemm2_kernel<<<dim3((tc * BATCH) / 128, DOUT / 64), 256, 0, stream>>>(
        spkc, w2h, w2l, b2, w2mx, cur2c);
    lif2_kernel<<<(BATCH * DOUT) / 256, 256, 0, stream>>>(cur2c, mem2, out + BATCH * DH, tc, init, save);
  }
}